// Round 15
// baseline (211.026 us; speedup 1.0000x reference)
//
#include <hip/hip_runtime.h>
#include <hip/hip_bf16.h>

#define B_ 32
#define T_ 4096
#define H_ 512
#define A_ 512
#define C_ 32
#define KTOT 544            // H + C (conv folded in as K-extension)
#define NKS  (KTOT / 32)    // 17 MFMA k-steps
#define TT   64             // t-tile rows per block
#define NCH  (T_ / TT)      // 64 t-chunks per batch

// LDS layout (bytes): A slots 17x4096 @0; B dbuf 2x32768 @69632; spart @135168; eL @136192
#define LDS_B0   69632
#define LDS_SP   135168
#define LDS_EL   136192
#define LDS_SZ   136448

typedef float f32x4 __attribute__((ext_vector_type(4)));
typedef __bf16 bf16x8 __attribute__((ext_vector_type(8)));

__device__ inline float fast_tanh(float x) {
    // tanh(x) = 1 - 2/(exp(2x)+1); exact at saturation, |err| ~1e-7
    float t = __expf(2.0f * x);
    return 1.0f - 2.0f / (t + 1.0f);
}

__device__ __forceinline__ void async16(const void* g, void* l) {
    __builtin_amdgcn_global_load_lds(
        (const __attribute__((address_space(1))) unsigned int*)g,
        (__attribute__((address_space(3))) unsigned int*)l, 16, 0, 0);
}

// ---------------- prep: dpb = dec@W^T + b ; V,U -> unified bf16 fragment buffer ----
// Vsall[(k>>3)*A + a]*8 + (k&7), k in [0,544). Per-kstep 32KB chunk contiguous.
__global__ __launch_bounds__(256) void prep_kernel(
    const float* __restrict__ dec, const float* __restrict__ W,
    const float* __restrict__ bvec, const float* __restrict__ V,
    const float* __restrict__ U,
    float* __restrict__ dpb, __bf16* __restrict__ Vsall) {
    int id = blockIdx.x * 256 + threadIdx.x;
    const int N1 = B_ * A_;          // 16384
    const int N2 = A_ * H_;          // 262144
    if (id < N1) {
        int b = id / A_, a = id % A_;
        const float* dr = dec + b * H_;
        const float* wr = W + (size_t)a * H_;
        float s = 0.f;
        #pragma unroll 8
        for (int h = 0; h < H_; ++h) s += dr[h] * wr[h];
        dpb[id] = s + bvec[a];
    } else if (id < N1 + N2) {
        int e = id - N1;
        int a = e >> 9, k = e & 511;
        Vsall[((k >> 3) * A_ + a) * 8 + (k & 7)] = (__bf16)V[(size_t)a * H_ + k];
    } else {
        int e = id - N1 - N2;        // 16384 U elements
        int a = e >> 5, c = e & 31;
        int k = H_ + c;
        Vsall[((k >> 3) * A_ + a) * 8 + (k & 7)] = (__bf16)U[a * C_ + c];
    }
}

// ---------------- fused scores + flash partials; A-tiles RETAINED in LDS ----------------
// r8/r14 structure: 64x512 tile, 8 waves, B dbuf via global_load_lds.
// A is written once per kstep into its own 4KB slot and kept; the u-epilogue
// reads enc back from LDS (bf16) instead of re-fetching 256MB from HBM.
__global__ __launch_bounds__(512) void scores_mfma(
    const float* __restrict__ enc, const float* __restrict__ align,
    const float* __restrict__ conv_w, const float* __restrict__ conv_b,
    const __bf16* __restrict__ Vsall, const float* __restrict__ dpb,
    const float* __restrict__ wvec, float* __restrict__ scores,
    float* __restrict__ ml_buf, float* __restrict__ u_buf) {
    const int bx = blockIdx.x;
    const int t0 = bx * TT;
    const int b  = blockIdx.y;
    const int tid = threadIdx.x;
    const int lane = tid & 63, wid = tid >> 6;
    const int row0 = lane & 15;   // C/D col lane
    const int kg   = lane >> 4;   // k-group 0..3 within the 32-k step
    const int wq   = wid & 3;     // col quarter
    const int wr   = wid >> 2;    // row half (32 rows)
    const int wcol = wq * 128;

    __shared__ char smem[LDS_SZ];
    float* spart = (float*)(smem + LDS_SP);  // [4][TT]
    float* eL    = (float*)(smem + LDS_EL);  // [TT]

    const float* encb = enc + ((size_t)b * T_ + t0) * H_;
    const int arow = tid >> 2, akgl = tid & 3;   // A staging assignment (tid<256)
    const int ag = tid ^ ((tid >> 4) & 7);       // swizzled unit (tid<256)

    // ---- stage kstep 0 ----
    {
        __bf16* bdst = (__bf16*)(smem + LDS_B0);
        #pragma unroll
        for (int i = 0; i < 4; ++i) {
            int u = i * 512 + tid;
            async16(Vsall + u * 8, bdst + u * 8);
        }
    }
    if (tid < 256) {
        const float* p = encb + arow * H_ + akgl * 8;
        f32x4 lo = *reinterpret_cast<const f32x4*>(p);
        f32x4 hi = *reinterpret_cast<const f32x4*>(p + 4);
        bf16x8 v;
        v[0] = (__bf16)lo.x; v[1] = (__bf16)lo.y; v[2] = (__bf16)lo.z; v[3] = (__bf16)lo.w;
        v[4] = (__bf16)hi.x; v[5] = (__bf16)hi.y; v[6] = (__bf16)hi.z; v[7] = (__bf16)hi.w;
        *reinterpret_cast<bf16x8*>(smem + ag * 16) = v;   // A slot 0
    }
    __syncthreads();

    f32x4 acc[2][8];
    #pragma unroll
    for (int m = 0; m < 2; ++m)
        #pragma unroll
        for (int n = 0; n < 8; ++n) acc[m][n] = (f32x4){0.f, 0.f, 0.f, 0.f};

    for (int ks = 0; ks < NKS; ++ks) {
        char* Acur = smem + ks * 4096;            // retained slot
        char* Anxt = smem + (ks + 1) * 4096;
        char* Bcur = smem + LDS_B0 + (ks & 1) * 32768;
        char* Bnxt = smem + LDS_B0 + ((ks + 1) & 1) * 32768;

        f32x4 alo, ahi;
        bool stage = (ks + 1 < NKS);
        bool conv_step = (ks + 1 == NKS - 1);
        if (stage) {
            const __bf16* vchunk = Vsall + (size_t)(ks + 1) * (4 * A_ * 8);
            #pragma unroll
            for (int i = 0; i < 4; ++i) {
                int u = i * 512 + tid;
                async16(vchunk + u * 8, (__bf16*)Bnxt + u * 8);
            }
            if (tid < 256 && !conv_step) {
                const float* p = encb + arow * H_ + (ks + 1) * 32 + akgl * 8;
                alo = *reinterpret_cast<const f32x4*>(p);
                ahi = *reinterpret_cast<const f32x4*>(p + 4);
            }
        }

        // ---- compute current k-step ----
        bf16x8 afrag[2];
        #pragma unroll
        for (int m = 0; m < 2; ++m) {
            int row = wr * 32 + m * 16 + row0;
            int u = row * 4 + kg;
            int g = u ^ ((u >> 4) & 7);
            afrag[m] = *reinterpret_cast<const bf16x8*>(Acur + g * 16);
        }
        const __bf16* bp = (const __bf16*)Bcur + kg * (A_ * 8);
        #pragma unroll
        for (int n = 0; n < 8; ++n) {
            bf16x8 bfrag = *reinterpret_cast<const bf16x8*>(bp + (wcol + n * 16 + row0) * 8);
            acc[0][n] = __builtin_amdgcn_mfma_f32_16x16x32_bf16(afrag[0], bfrag, acc[0][n], 0, 0, 0);
            acc[1][n] = __builtin_amdgcn_mfma_f32_16x16x32_bf16(afrag[1], bfrag, acc[1][n], 0, 0, 0);
        }

        // ---- write A(ks+1) into its slot ----
        if (stage && tid < 256) {
            bf16x8 v;
            if (!conv_step) {
                v[0] = (__bf16)alo.x; v[1] = (__bf16)alo.y; v[2] = (__bf16)alo.z; v[3] = (__bf16)alo.w;
                v[4] = (__bf16)ahi.x; v[5] = (__bf16)ahi.y; v[6] = (__bf16)ahi.z; v[7] = (__bf16)ahi.w;
            } else {
                int t = t0 + arow;
                float x0 = (t > 0) ? align[b * T_ + t - 1] : 0.f;
                float x1 = align[b * T_ + t];
                float x2 = (t + 1 < T_) ? align[b * T_ + t + 1] : 0.f;
                #pragma unroll
                for (int e = 0; e < 8; ++e) {
                    int c = akgl * 8 + e;
                    v[e] = (__bf16)(conv_b[c] + conv_w[c * 3 + 0] * x0
                                  + conv_w[c * 3 + 1] * x1 + conv_w[c * 3 + 2] * x2);
                }
            }
            *reinterpret_cast<bf16x8*>(Anxt + ag * 16) = v;
        }
        __syncthreads();
    }

    // ---- epilogue 1: tanh(acc + dpb)*w, reduce over A -> scores ----
    float dval[8], wv[8];
    #pragma unroll
    for (int n = 0; n < 8; ++n) {
        int a = wcol + n * 16 + row0;
        dval[n] = dpb[b * A_ + a];
        wv[n]   = wvec[a];
    }
    #pragma unroll
    for (int m = 0; m < 2; ++m) {
        float rs[4] = {0.f, 0.f, 0.f, 0.f};
        #pragma unroll
        for (int n = 0; n < 8; ++n) {
            #pragma unroll
            for (int j = 0; j < 4; ++j) {
                float x = acc[m][n][j] + dval[n];
                rs[j] += fast_tanh(x) * wv[n];
            }
        }
        #pragma unroll
        for (int j = 0; j < 4; ++j) {
            float v = rs[j];
            v += __shfl_xor(v, 1);
            v += __shfl_xor(v, 2);
            v += __shfl_xor(v, 4);
            v += __shfl_xor(v, 8);
            if (row0 == 0) spart[wq * TT + wr * 32 + m * 16 + kg * 4 + j] = v;
        }
    }
    __syncthreads();

    // ---- epilogue 2: chunk partials m_c, l_c ----
    if (tid < TT) {   // wave 0 exactly
        float s = spart[0 * TT + tid] + spart[1 * TT + tid]
                + spart[2 * TT + tid] + spart[3 * TT + tid];
        scores[b * T_ + t0 + tid] = s;
        float mx = s;
        #pragma unroll
        for (int off = 32; off >= 1; off >>= 1) mx = fmaxf(mx, __shfl_xor(mx, off));
        float e = __expf(s - mx);
        eL[tid] = e;
        float l = e;
        #pragma unroll
        for (int off = 32; off >= 1; off >>= 1) l += __shfl_xor(l, off);
        if (tid == 0) {
            ml_buf[((size_t)b * NCH + bx) * 2 + 0] = mx;
            ml_buf[((size_t)b * NCH + bx) * 2 + 1] = l;
        }
    }
    __syncthreads();

    // ---- epilogue 3: u[h] = sum_t eL[t] * enc_bf16[t][h] from retained LDS ----
    {
        const int ksh = tid >> 5;          // A slot 0..15 (h<512, conv slot untouched)
        const int kqh = (tid >> 3) & 3;
        const int eh  = tid & 7;
        const char* base = smem + ksh * 4096 + eh * 2;
        float u0 = 0.f, u1 = 0.f;
        #pragma unroll 8
        for (int t = 0; t < TT; t += 2) {
            int ua = t * 4 + kqh;
            int ub = ua + 4;
            int ga = ua ^ ((ua >> 4) & 7);
            int gb = ub ^ ((ub >> 4) & 7);
            u0 += eL[t]     * (float)(*(const __bf16*)(base + ga * 16));
            u1 += eL[t + 1] * (float)(*(const __bf16*)(base + gb * 16));
        }
        u_buf[((size_t)b * NCH + bx) * H_ + tid] = u0 + u1;
    }
}

// ---------------- softmax over T per batch; fp32 alignment into d_out ----------------
__global__ __launch_bounds__(256) void softmax_k(
    const float* __restrict__ scores, float* __restrict__ out_align) {
    int b = blockIdx.x;
    int tid = threadIdx.x;
    __shared__ float redm[4];
    __shared__ float reds[4];
    float local[16];
    float mx = -1e30f;
    #pragma unroll
    for (int i = 0; i < 16; ++i) {
        float s = scores[b * T_ + tid + i * 256];
        local[i] = s;
        mx = fmaxf(mx, s);
    }
    for (int off = 32; off >= 1; off >>= 1) mx = fmaxf(mx, __shfl_xor(mx, off));
    if ((tid & 63) == 0) redm[tid >> 6] = mx;
    __syncthreads();
    mx = fmaxf(fmaxf(redm[0], redm[1]), fmaxf(redm[2], redm[3]));
    float sum = 0.f;
    #pragma unroll
    for (int i = 0; i < 16; ++i) { local[i] = __expf(local[i] - mx); sum += local[i]; }
    for (int off = 32; off >= 1; off >>= 1) sum += __shfl_xor(sum, off);
    if ((tid & 63) == 0) reds[tid >> 6] = sum;
    __syncthreads();
    sum = reds[0] + reds[1] + reds[2] + reds[3];
    float inv = 1.0f / sum;
    #pragma unroll
    for (int i = 0; i < 16; ++i)
        out_align[b * T_ + tid + i * 256] = local[i] * inv;
}

// ---------------- combine2: out[b][h] = sum_c w_c u_c[h] / sum_c w_c l_c ----------------
__global__ __launch_bounds__(512) void combine2_k(
    const float* __restrict__ ml_buf, const float* __restrict__ u_buf,
    float* __restrict__ out) {
    int b = blockIdx.x;
    int h = threadIdx.x;
    __shared__ float wsh[NCH];
    __shared__ float dsh[1];
    if (h < NCH) {
        float m = ml_buf[((size_t)b * NCH + h) * 2];
        float mb = m;
        #pragma unroll
        for (int off = 32; off >= 1; off >>= 1) mb = fmaxf(mb, __shfl_xor(mb, off));
        float w = __expf(m - mb);
        wsh[h] = w;
        float d = w * ml_buf[((size_t)b * NCH + h) * 2 + 1];
        #pragma unroll
        for (int off = 32; off >= 1; off >>= 1) d += __shfl_xor(d, off);
        if (h == 0) dsh[0] = d;
    }
    __syncthreads();
    float acc = 0.f;
    #pragma unroll 4
    for (int c = 0; c < NCH; ++c)
        acc += wsh[c] * u_buf[((size_t)b * NCH + c) * H_ + h];
    out[b * H_ + h] = acc / dsh[0];
}

extern "C" void kernel_launch(void* const* d_in, const int* in_sizes, int n_in,
                              void* d_out, int out_size, void* d_ws, size_t ws_size,
                              hipStream_t stream) {
    const float* dec    = (const float*)d_in[0];
    const float* enc    = (const float*)d_in[1];
    const float* align  = (const float*)d_in[2];
    const float* conv_w = (const float*)d_in[3];
    const float* conv_b = (const float*)d_in[4];
    const float* W      = (const float*)d_in[5];
    const float* V      = (const float*)d_in[6];
    const float* U      = (const float*)d_in[7];
    const float* bvec   = (const float*)d_in[8];
    const float* wvec   = (const float*)d_in[9];
    float* out       = (float*)d_out;           // output[B,H] fp32
    float* out_align = out + B_ * H_;           // alignment[B,T] fp32

    char* ws = (char*)d_ws;
    float*  dpb    = (float*)(ws);                   // 64 KB
    float*  scores = (float*)(ws + (64 << 10));      // 512 KB
    float*  ml_buf = (float*)(ws + (576 << 10));     // 16 KB
    float*  u_buf  = (float*)(ws + (592 << 10));     // 4 MB
    __bf16* Vsall  = (__bf16*)(ws + (592 << 10) + (4 << 20));   // 544 KB

    prep_kernel<<<(B_ * A_ + A_ * H_ + A_ * C_) / 256, 256, 0, stream>>>(
        dec, W, bvec, V, U, dpb, Vsall);
    scores_mfma<<<dim3(T_ / TT, B_), 512, 0, stream>>>(enc, align, conv_w, conv_b,
                                                       Vsall, dpb, wvec, scores,
                                                       ml_buf, u_buf);
    softmax_k<<<B_, 256, 0, stream>>>(scores, out_align);
    combine2_k<<<B_, 512, 0, stream>>>(ml_buf, u_buf, out);
}

// Round 16
// 166.428 us; speedup vs baseline: 1.2680x; 1.2680x over previous
//
#include <hip/hip_runtime.h>
#include <hip/hip_bf16.h>

#define B_ 32
#define T_ 4096
#define H_ 512
#define A_ 512
#define C_ 32
#define KTOT 544            // H + C (conv folded in as K-extension)
#define NKS  (KTOT / 32)    // 17 MFMA k-steps
#define TT   64             // t-tile rows per block
#define NCH  (T_ / TT)      // 64 t-chunks per batch

typedef float f32x4 __attribute__((ext_vector_type(4)));
typedef __bf16 bf16x8 __attribute__((ext_vector_type(8)));

__device__ inline float fast_tanh(float x) {
    // tanh(x) = 1 - 2/(exp(2x)+1); exact at saturation, |err| ~1e-7
    float t = __expf(2.0f * x);
    return 1.0f - 2.0f / (t + 1.0f);
}

__device__ __forceinline__ void async16(const void* g, void* l) {
    __builtin_amdgcn_global_load_lds(
        (const __attribute__((address_space(1))) unsigned int*)g,
        (__attribute__((address_space(3))) unsigned int*)l, 16, 0, 0);
}

// ---------------- prep: dpb = dec@W^T + b ; V,U -> unified bf16 fragment buffer ----
// Vsall[(k>>3)*A + a]*8 + (k&7), k in [0,544). Per-kstep 32KB chunk contiguous.
__global__ __launch_bounds__(256) void prep_kernel(
    const float* __restrict__ dec, const float* __restrict__ W,
    const float* __restrict__ bvec, const float* __restrict__ V,
    const float* __restrict__ U,
    float* __restrict__ dpb, __bf16* __restrict__ Vsall) {
    int id = blockIdx.x * 256 + threadIdx.x;
    const int N1 = B_ * A_;          // 16384
    const int N2 = A_ * H_;          // 262144
    if (id < N1) {
        int b = id / A_, a = id % A_;
        const float* dr = dec + b * H_;
        const float* wr = W + (size_t)a * H_;
        float s = 0.f;
        #pragma unroll 8
        for (int h = 0; h < H_; ++h) s += dr[h] * wr[h];
        dpb[id] = s + bvec[a];
    } else if (id < N1 + N2) {
        int e = id - N1;
        int a = e >> 9, k = e & 511;
        Vsall[((k >> 3) * A_ + a) * 8 + (k & 7)] = (__bf16)V[(size_t)a * H_ + k];
    } else {
        int e = id - N1 - N2;        // 16384 U elements
        int a = e >> 5, c = e & 31;
        int k = H_ + c;
        Vsall[((k >> 3) * A_ + a) * 8 + (k & 7)] = (__bf16)U[a * C_ + c];
    }
}

// ---------------- fused scores + flash-style output partials (r14 verified) ----------------
__global__ __launch_bounds__(512) void scores_mfma(
    const float* __restrict__ enc, const float* __restrict__ align,
    const float* __restrict__ conv_w, const float* __restrict__ conv_b,
    const __bf16* __restrict__ Vsall, const float* __restrict__ dpb,
    const float* __restrict__ wvec, float* __restrict__ scores,
    float* __restrict__ ml_buf, float* __restrict__ u_buf) {
    const int bx = blockIdx.x;
    const int t0 = bx * TT;
    const int b  = blockIdx.y;
    const int tid = threadIdx.x;
    const int lane = tid & 63, wid = tid >> 6;
    const int row0 = lane & 15;   // C/D col lane
    const int kg   = lane >> 4;   // k-group 0..3 within the 32-k step
    const int wq   = wid & 3;     // col quarter
    const int wr   = wid >> 2;    // row half (32 rows)
    const int wcol = wq * 128;

    __shared__ char smem[73728];  // A dbuf 2x4KB @0, B dbuf 2x32KB @8192
    float* spart = (float*)smem;  // [4][TT] = 1KB, aliases A after the loop
    float* eL    = (float*)(smem + 2048);   // [TT] exp values (aliases A buf 0)

    const float* encb = enc + ((size_t)b * T_ + t0) * H_;
    const int arow = tid >> 2, akgl = tid & 3;   // A staging assignment (tid<256)

    // ---- stage kstep 0 ----
    {
        __bf16* bdst = (__bf16*)(smem + 8192);
        #pragma unroll
        for (int i = 0; i < 4; ++i) {
            int u = i * 512 + tid;
            async16(Vsall + u * 8, bdst + u * 8);
        }
    }
    if (tid < 256) {
        const float* p = encb + arow * H_ + akgl * 8;
        f32x4 lo = *reinterpret_cast<const f32x4*>(p);
        f32x4 hi = *reinterpret_cast<const f32x4*>(p + 4);
        bf16x8 v;
        v[0] = (__bf16)lo.x; v[1] = (__bf16)lo.y; v[2] = (__bf16)lo.z; v[3] = (__bf16)lo.w;
        v[4] = (__bf16)hi.x; v[5] = (__bf16)hi.y; v[6] = (__bf16)hi.z; v[7] = (__bf16)hi.w;
        int g = tid ^ ((tid >> 4) & 7);
        *reinterpret_cast<bf16x8*>((__bf16*)smem + g * 8) = v;
    }
    __syncthreads();

    f32x4 acc[2][8];
    #pragma unroll
    for (int m = 0; m < 2; ++m)
        #pragma unroll
        for (int n = 0; n < 8; ++n) acc[m][n] = (f32x4){0.f, 0.f, 0.f, 0.f};

    int cur = 0;
    for (int ks = 0; ks < NKS; ++ks) {
        __bf16* Acur = (__bf16*)(smem + (cur ? 4096 : 0));
        __bf16* Anxt = (__bf16*)(smem + (cur ? 0 : 4096));
        __bf16* Bcur = (__bf16*)(smem + 8192 + (cur ? 32768 : 0));
        __bf16* Bnxt = (__bf16*)(smem + 8192 + (cur ? 0 : 32768));

        f32x4 alo, ahi;
        bool stage = (ks + 1 < NKS);
        bool conv_step = (ks + 1 == NKS - 1);
        if (stage) {
            const __bf16* vchunk = Vsall + (size_t)(ks + 1) * (4 * A_ * 8);
            #pragma unroll
            for (int i = 0; i < 4; ++i) {
                int u = i * 512 + tid;
                async16(vchunk + u * 8, Bnxt + u * 8);
            }
            if (tid < 256 && !conv_step) {
                const float* p = encb + arow * H_ + (ks + 1) * 32 + akgl * 8;
                alo = *reinterpret_cast<const f32x4*>(p);
                ahi = *reinterpret_cast<const f32x4*>(p + 4);
            }
        }

        // ---- compute current k-step ----
        bf16x8 afrag[2];
        #pragma unroll
        for (int m = 0; m < 2; ++m) {
            int row = wr * 32 + m * 16 + row0;
            int u = row * 4 + kg;
            int g = u ^ ((u >> 4) & 7);
            afrag[m] = *reinterpret_cast<const bf16x8*>(Acur + g * 8);
        }
        const __bf16* bp = Bcur + kg * (A_ * 8);
        #pragma unroll
        for (int n = 0; n < 8; ++n) {
            bf16x8 bfrag = *reinterpret_cast<const bf16x8*>(bp + (wcol + n * 16 + row0) * 8);
            acc[0][n] = __builtin_amdgcn_mfma_f32_16x16x32_bf16(afrag[0], bfrag, acc[0][n], 0, 0, 0);
            acc[1][n] = __builtin_amdgcn_mfma_f32_16x16x32_bf16(afrag[1], bfrag, acc[1][n], 0, 0, 0);
        }

        // ---- write A-next to LDS ----
        if (stage && tid < 256) {
            bf16x8 v;
            if (!conv_step) {
                v[0] = (__bf16)alo.x; v[1] = (__bf16)alo.y; v[2] = (__bf16)alo.z; v[3] = (__bf16)alo.w;
                v[4] = (__bf16)ahi.x; v[5] = (__bf16)ahi.y; v[6] = (__bf16)ahi.z; v[7] = (__bf16)ahi.w;
            } else {
                int t = t0 + arow;
                float x0 = (t > 0) ? align[b * T_ + t - 1] : 0.f;
                float x1 = align[b * T_ + t];
                float x2 = (t + 1 < T_) ? align[b * T_ + t + 1] : 0.f;
                #pragma unroll
                for (int e = 0; e < 8; ++e) {
                    int c = akgl * 8 + e;
                    v[e] = (__bf16)(conv_b[c] + conv_w[c * 3 + 0] * x0
                                  + conv_w[c * 3 + 1] * x1 + conv_w[c * 3 + 2] * x2);
                }
            }
            int g = tid ^ ((tid >> 4) & 7);
            *reinterpret_cast<bf16x8*>(Anxt + g * 8) = v;
        }
        __syncthreads();
        cur ^= 1;
    }

    // ---- epilogue 1: tanh(acc + dpb)*w, reduce over A -> scores ----
    float dval[8], wv[8];
    #pragma unroll
    for (int n = 0; n < 8; ++n) {
        int a = wcol + n * 16 + row0;
        dval[n] = dpb[b * A_ + a];
        wv[n]   = wvec[a];
    }
    #pragma unroll
    for (int m = 0; m < 2; ++m) {
        float rs[4] = {0.f, 0.f, 0.f, 0.f};
        #pragma unroll
        for (int n = 0; n < 8; ++n) {
            #pragma unroll
            for (int j = 0; j < 4; ++j) {
                float x = acc[m][n][j] + dval[n];
                rs[j] += fast_tanh(x) * wv[n];
            }
        }
        #pragma unroll
        for (int j = 0; j < 4; ++j) {
            float v = rs[j];
            v += __shfl_xor(v, 1);
            v += __shfl_xor(v, 2);
            v += __shfl_xor(v, 4);
            v += __shfl_xor(v, 8);
            if (row0 == 0) spart[wq * TT + wr * 32 + m * 16 + kg * 4 + j] = v;
        }
    }
    __syncthreads();

    // ---- epilogue 2: chunk partials m_c, l_c ----
    if (tid < TT) {   // wave 0 exactly (TT=64)
        float s = spart[0 * TT + tid] + spart[1 * TT + tid]
                + spart[2 * TT + tid] + spart[3 * TT + tid];
        scores[b * T_ + t0 + tid] = s;
        float mx = s;
        #pragma unroll
        for (int off = 32; off >= 1; off >>= 1) mx = fmaxf(mx, __shfl_xor(mx, off));
        float e = __expf(s - mx);
        eL[tid] = e;
        float l = e;
        #pragma unroll
        for (int off = 32; off >= 1; off >>= 1) l += __shfl_xor(l, off);
        if (tid == 0) {
            ml_buf[((size_t)b * NCH + bx) * 2 + 0] = mx;
            ml_buf[((size_t)b * NCH + bx) * 2 + 1] = l;
        }
    }
    __syncthreads();
    // ---- epilogue 3: u[h] = sum_t eL[t] * enc[t][h] ----
    {
        float u0 = 0.f, u1 = 0.f, u2 = 0.f, u3 = 0.f;
        const float* ep = encb + tid;
        #pragma unroll 4
        for (int t = 0; t < TT; t += 4) {
            u0 += eL[t]     * ep[(size_t)t * H_];
            u1 += eL[t + 1] * ep[(size_t)(t + 1) * H_];
            u2 += eL[t + 2] * ep[(size_t)(t + 2) * H_];
            u3 += eL[t + 3] * ep[(size_t)(t + 3) * H_];
        }
        u_buf[((size_t)b * NCH + bx) * H_ + tid] = (u0 + u1) + (u2 + u3);
    }
}

// ---------------- combine2: out[b][h] = sum_c w_c u_c[h] / denom; persist m_b, denom ----
__global__ __launch_bounds__(512) void combine2_k(
    const float* __restrict__ ml_buf, const float* __restrict__ u_buf,
    float* __restrict__ out, float* __restrict__ mden) {
    int b = blockIdx.x;
    int h = threadIdx.x;
    __shared__ float wsh[NCH];
    __shared__ float dsh[2];
    if (h < NCH) {
        float m = ml_buf[((size_t)b * NCH + h) * 2];
        float mb = m;
        #pragma unroll
        for (int off = 32; off >= 1; off >>= 1) mb = fmaxf(mb, __shfl_xor(mb, off));
        float w = __expf(m - mb);
        wsh[h] = w;
        float d = w * ml_buf[((size_t)b * NCH + h) * 2 + 1];
        #pragma unroll
        for (int off = 32; off >= 1; off >>= 1) d += __shfl_xor(d, off);
        if (h == 0) {
            dsh[0] = d;
            dsh[1] = mb;
            mden[b * 2 + 0] = mb;
            mden[b * 2 + 1] = d;
        }
    }
    __syncthreads();
    float acc = 0.f;
    #pragma unroll 4
    for (int c = 0; c < NCH; ++c)
        acc += wsh[c] * u_buf[((size_t)b * NCH + c) * H_ + h];
    out[b * H_ + h] = acc / dsh[0];
}

// ---------------- align_k: fully parallel elementwise alignment ----------------
// alpha[b][t] = exp(scores[b][t] - m_b) / denom_b   (identical algebra to softmax)
__global__ __launch_bounds__(512) void align_k(
    const float* __restrict__ scores, const float* __restrict__ mden,
    float* __restrict__ out_align) {
    int idx = blockIdx.x * 512 + threadIdx.x;   // 256 blocks x 512 = B*T
    int b = idx >> 12;                          // T_ = 4096
    float m = mden[b * 2 + 0];
    float inv = 1.0f / mden[b * 2 + 1];
    out_align[idx] = __expf(scores[idx] - m) * inv;
}

extern "C" void kernel_launch(void* const* d_in, const int* in_sizes, int n_in,
                              void* d_out, int out_size, void* d_ws, size_t ws_size,
                              hipStream_t stream) {
    const float* dec    = (const float*)d_in[0];
    const float* enc    = (const float*)d_in[1];
    const float* align  = (const float*)d_in[2];
    const float* conv_w = (const float*)d_in[3];
    const float* conv_b = (const float*)d_in[4];
    const float* W      = (const float*)d_in[5];
    const float* V      = (const float*)d_in[6];
    const float* U      = (const float*)d_in[7];
    const float* bvec   = (const float*)d_in[8];
    const float* wvec   = (const float*)d_in[9];
    float* out       = (float*)d_out;           // output[B,H] fp32
    float* out_align = out + B_ * H_;           // alignment[B,T] fp32

    char* ws = (char*)d_ws;
    float*  dpb    = (float*)(ws);                   // 64 KB
    float*  scores = (float*)(ws + (64 << 10));      // 512 KB
    float*  ml_buf = (float*)(ws + (576 << 10));     // 16 KB
    float*  u_buf  = (float*)(ws + (592 << 10));     // 4 MB
    __bf16* Vsall  = (__bf16*)(ws + (592 << 10) + (4 << 20));   // 544 KB
    float*  mden   = (float*)(ws + (592 << 10) + (4 << 20) + (544 << 10));  // 256 B

    prep_kernel<<<(B_ * A_ + A_ * H_ + A_ * C_) / 256, 256, 0, stream>>>(
        dec, W, bvec, V, U, dpb, Vsall);
    scores_mfma<<<dim3(T_ / TT, B_), 512, 0, stream>>>(enc, align, conv_w, conv_b,
                                                       Vsall, dpb, wvec, scores,
                                                       ml_buf, u_buf);
    combine2_k<<<B_, 512, 0, stream>>>(ml_buf, u_buf, out, mden);
    align_k<<<(B_ * T_) / 512, 512, 0, stream>>>(scores, mden, out_align);
}

// Round 17
// 163.802 us; speedup vs baseline: 1.2883x; 1.0160x over previous
//
#include <hip/hip_runtime.h>
#include <hip/hip_bf16.h>

#define B_ 32
#define T_ 4096
#define H_ 512
#define A_ 512
#define C_ 32
#define KTOT 544            // H + C (conv folded in as K-extension)
#define NKS  (KTOT / 32)    // 17 MFMA k-steps
#define TT   64             // t-tile rows per block
#define NCH  (T_ / TT)      // 64 t-chunks per batch

typedef float f32x4 __attribute__((ext_vector_type(4)));
typedef __bf16 bf16x8 __attribute__((ext_vector_type(8)));

__device__ inline float fast_tanh(float x) {
    // tanh(x) = 1 - 2/(exp(2x)+1); exact at saturation, |err| ~1e-7
    float t = __expf(2.0f * x);
    return 1.0f - 2.0f / (t + 1.0f);
}

__device__ __forceinline__ void async16(const void* g, void* l) {
    __builtin_amdgcn_global_load_lds(
        (const __attribute__((address_space(1))) unsigned int*)g,
        (__attribute__((address_space(3))) unsigned int*)l, 16, 0, 0);
}

// ---------------- prep: dpb = dec@W^T + b ; V,U -> unified bf16 fragment buffer ----
// Vsall[(k>>3)*A + a]*8 + (k&7), k in [0,544). Per-kstep 32KB chunk contiguous.
__global__ __launch_bounds__(256) void prep_kernel(
    const float* __restrict__ dec, const float* __restrict__ W,
    const float* __restrict__ bvec, const float* __restrict__ V,
    const float* __restrict__ U,
    float* __restrict__ dpb, __bf16* __restrict__ Vsall) {
    int id = blockIdx.x * 256 + threadIdx.x;
    const int N1 = B_ * A_;          // 16384
    const int N2 = A_ * H_;          // 262144
    if (id < N1) {
        int b = id / A_, a = id % A_;
        const float* dr = dec + b * H_;
        const float* wr = W + (size_t)a * H_;
        float s = 0.f;
        #pragma unroll 8
        for (int h = 0; h < H_; ++h) s += dr[h] * wr[h];
        dpb[id] = s + bvec[a];
    } else if (id < N1 + N2) {
        int e = id - N1;
        int a = e >> 9, k = e & 511;
        Vsall[((k >> 3) * A_ + a) * 8 + (k & 7)] = (__bf16)V[(size_t)a * H_ + k];
    } else {
        int e = id - N1 - N2;        // 16384 U elements
        int a = e >> 5, c = e & 31;
        int k = H_ + c;
        Vsall[((k >> 3) * A_ + a) * 8 + (k & 7)] = (__bf16)U[a * C_ + c];
    }
}

// ---------------- fused scores + flash partials; 64x64 wave tiles (B-read dedup) ----
// 8 waves, each owns ALL 64 rows x a 64-col slice: 4 A-frag + 4 B-frag reads per
// kstep (64 reads/block-kstep vs 80 in the 32x128 tiling). Schedule = r16 verified.
__global__ __launch_bounds__(512) void scores_mfma(
    const float* __restrict__ enc, const float* __restrict__ align,
    const float* __restrict__ conv_w, const float* __restrict__ conv_b,
    const __bf16* __restrict__ Vsall, const float* __restrict__ dpb,
    const float* __restrict__ wvec, float* __restrict__ scores,
    float* __restrict__ ml_buf, float* __restrict__ u_buf) {
    const int bx = blockIdx.x;
    const int t0 = bx * TT;
    const int b  = blockIdx.y;
    const int tid = threadIdx.x;
    const int lane = tid & 63, wid = tid >> 6;
    const int row0 = lane & 15;   // C/D a-col lane; A-frag row-within-16
    const int kg   = lane >> 4;   // k-group 0..3 within the 32-k step
    const int wcol = wid * 64;    // wave's exclusive 64-col slice

    __shared__ char smem[73728];  // A dbuf 2x4KB @0, B dbuf 2x32KB @8192
    float* spart = (float*)smem;  // [8][TT] = 2KB, aliases A after the loop
    float* eL    = (float*)(smem + 2048);   // [TT] exp values (aliases A buf 0)

    const float* encb = enc + ((size_t)b * T_ + t0) * H_;
    const int arow = tid >> 2, akgl = tid & 3;   // A staging assignment (tid<256)

    // ---- stage kstep 0 ----
    {
        __bf16* bdst = (__bf16*)(smem + 8192);
        #pragma unroll
        for (int i = 0; i < 4; ++i) {
            int u = i * 512 + tid;
            async16(Vsall + u * 8, bdst + u * 8);
        }
    }
    if (tid < 256) {
        const float* p = encb + arow * H_ + akgl * 8;
        f32x4 lo = *reinterpret_cast<const f32x4*>(p);
        f32x4 hi = *reinterpret_cast<const f32x4*>(p + 4);
        bf16x8 v;
        v[0] = (__bf16)lo.x; v[1] = (__bf16)lo.y; v[2] = (__bf16)lo.z; v[3] = (__bf16)lo.w;
        v[4] = (__bf16)hi.x; v[5] = (__bf16)hi.y; v[6] = (__bf16)hi.z; v[7] = (__bf16)hi.w;
        int g = tid ^ ((tid >> 4) & 7);
        *reinterpret_cast<bf16x8*>((__bf16*)smem + g * 8) = v;
    }
    __syncthreads();

    f32x4 acc[4][4];
    #pragma unroll
    for (int m = 0; m < 4; ++m)
        #pragma unroll
        for (int n = 0; n < 4; ++n) acc[m][n] = (f32x4){0.f, 0.f, 0.f, 0.f};

    int cur = 0;
    for (int ks = 0; ks < NKS; ++ks) {
        __bf16* Acur = (__bf16*)(smem + (cur ? 4096 : 0));
        __bf16* Anxt = (__bf16*)(smem + (cur ? 0 : 4096));
        __bf16* Bcur = (__bf16*)(smem + 8192 + (cur ? 32768 : 0));
        __bf16* Bnxt = (__bf16*)(smem + 8192 + (cur ? 0 : 32768));

        f32x4 alo, ahi;
        bool stage = (ks + 1 < NKS);
        bool conv_step = (ks + 1 == NKS - 1);
        if (stage) {
            const __bf16* vchunk = Vsall + (size_t)(ks + 1) * (4 * A_ * 8);
            #pragma unroll
            for (int i = 0; i < 4; ++i) {
                int u = i * 512 + tid;
                async16(vchunk + u * 8, Bnxt + u * 8);
            }
            if (tid < 256 && !conv_step) {
                const float* p = encb + arow * H_ + (ks + 1) * 32 + akgl * 8;
                alo = *reinterpret_cast<const f32x4*>(p);
                ahi = *reinterpret_cast<const f32x4*>(p + 4);
            }
        }

        // ---- compute current k-step: 4 A reads + 4 B reads + 16 MFMA ----
        bf16x8 afrag[4];
        #pragma unroll
        for (int m = 0; m < 4; ++m) {
            int row = m * 16 + row0;
            int u = row * 4 + kg;
            int g = u ^ ((u >> 4) & 7);
            afrag[m] = *reinterpret_cast<const bf16x8*>(Acur + g * 8);
        }
        const __bf16* bp = Bcur + kg * (A_ * 8);
        #pragma unroll
        for (int n = 0; n < 4; ++n) {
            bf16x8 bfrag = *reinterpret_cast<const bf16x8*>(bp + (wcol + n * 16 + row0) * 8);
            #pragma unroll
            for (int m = 0; m < 4; ++m)
                acc[m][n] = __builtin_amdgcn_mfma_f32_16x16x32_bf16(afrag[m], bfrag, acc[m][n], 0, 0, 0);
        }

        // ---- write A-next to LDS ----
        if (stage && tid < 256) {
            bf16x8 v;
            if (!conv_step) {
                v[0] = (__bf16)alo.x; v[1] = (__bf16)alo.y; v[2] = (__bf16)alo.z; v[3] = (__bf16)alo.w;
                v[4] = (__bf16)ahi.x; v[5] = (__bf16)ahi.y; v[6] = (__bf16)ahi.z; v[7] = (__bf16)ahi.w;
            } else {
                int t = t0 + arow;
                float x0 = (t > 0) ? align[b * T_ + t - 1] : 0.f;
                float x1 = align[b * T_ + t];
                float x2 = (t + 1 < T_) ? align[b * T_ + t + 1] : 0.f;
                #pragma unroll
                for (int e = 0; e < 8; ++e) {
                    int c = akgl * 8 + e;
                    v[e] = (__bf16)(conv_b[c] + conv_w[c * 3 + 0] * x0
                                  + conv_w[c * 3 + 1] * x1 + conv_w[c * 3 + 2] * x2);
                }
            }
            int g = tid ^ ((tid >> 4) & 7);
            *reinterpret_cast<bf16x8*>(Anxt + g * 8) = v;
        }
        __syncthreads();
        cur ^= 1;
    }

    // ---- epilogue 1: tanh(acc + dpb)*w, partial-reduce over this wave's 64 cols ----
    float dval[4], wv[4];
    #pragma unroll
    for (int n = 0; n < 4; ++n) {
        int a = wcol + n * 16 + row0;
        dval[n] = dpb[b * A_ + a];
        wv[n]   = wvec[a];
    }
    #pragma unroll
    for (int m = 0; m < 4; ++m) {
        float rs[4] = {0.f, 0.f, 0.f, 0.f};
        #pragma unroll
        for (int n = 0; n < 4; ++n) {
            #pragma unroll
            for (int j = 0; j < 4; ++j) {
                float x = acc[m][n][j] + dval[n];
                rs[j] += fast_tanh(x) * wv[n];
            }
        }
        #pragma unroll
        for (int j = 0; j < 4; ++j) {
            float v = rs[j];
            v += __shfl_xor(v, 1);
            v += __shfl_xor(v, 2);
            v += __shfl_xor(v, 4);
            v += __shfl_xor(v, 8);
            if (row0 == 0) spart[wid * TT + m * 16 + kg * 4 + j] = v;  // row = m*16+kg*4+j
        }
    }
    __syncthreads();

    // ---- epilogue 2: chunk partials m_c, l_c ----
    if (tid < TT) {   // wave 0 exactly (TT=64)
        float s = 0.f;
        #pragma unroll
        for (int w = 0; w < 8; ++w) s += spart[w * TT + tid];
        scores[b * T_ + t0 + tid] = s;
        float mx = s;
        #pragma unroll
        for (int off = 32; off >= 1; off >>= 1) mx = fmaxf(mx, __shfl_xor(mx, off));
        float e = __expf(s - mx);
        eL[tid] = e;
        float l = e;
        #pragma unroll
        for (int off = 32; off >= 1; off >>= 1) l += __shfl_xor(l, off);
        if (tid == 0) {
            ml_buf[((size_t)b * NCH + bx) * 2 + 0] = mx;
            ml_buf[((size_t)b * NCH + bx) * 2 + 1] = l;
        }
    }
    __syncthreads();
    // ---- epilogue 3: u[h] = sum_t eL[t] * enc[t][h] ----
    {
        float u0 = 0.f, u1 = 0.f, u2 = 0.f, u3 = 0.f;
        const float* ep = encb + tid;
        #pragma unroll 4
        for (int t = 0; t < TT; t += 4) {
            u0 += eL[t]     * ep[(size_t)t * H_];
            u1 += eL[t + 1] * ep[(size_t)(t + 1) * H_];
            u2 += eL[t + 2] * ep[(size_t)(t + 2) * H_];
            u3 += eL[t + 3] * ep[(size_t)(t + 3) * H_];
        }
        u_buf[((size_t)b * NCH + bx) * H_ + tid] = (u0 + u1) + (u2 + u3);
    }
}

// ---------------- combine2: out[b][h] = sum_c w_c u_c[h] / denom; persist m_b, denom ----
__global__ __launch_bounds__(512) void combine2_k(
    const float* __restrict__ ml_buf, const float* __restrict__ u_buf,
    float* __restrict__ out, float* __restrict__ mden) {
    int b = blockIdx.x;
    int h = threadIdx.x;
    __shared__ float wsh[NCH];
    __shared__ float dsh[2];
    if (h < NCH) {
        float m = ml_buf[((size_t)b * NCH + h) * 2];
        float mb = m;
        #pragma unroll
        for (int off = 32; off >= 1; off >>= 1) mb = fmaxf(mb, __shfl_xor(mb, off));
        float w = __expf(m - mb);
        wsh[h] = w;
        float d = w * ml_buf[((size_t)b * NCH + h) * 2 + 1];
        #pragma unroll
        for (int off = 32; off >= 1; off >>= 1) d += __shfl_xor(d, off);
        if (h == 0) {
            dsh[0] = d;
            dsh[1] = mb;
            mden[b * 2 + 0] = mb;
            mden[b * 2 + 1] = d;
        }
    }
    __syncthreads();
    float acc = 0.f;
    #pragma unroll 4
    for (int c = 0; c < NCH; ++c)
        acc += wsh[c] * u_buf[((size_t)b * NCH + c) * H_ + h];
    out[b * H_ + h] = acc / dsh[0];
}

// ---------------- align_k: fully parallel elementwise alignment ----------------
__global__ __launch_bounds__(512) void align_k(
    const float* __restrict__ scores, const float* __restrict__ mden,
    float* __restrict__ out_align) {
    int idx = blockIdx.x * 512 + threadIdx.x;   // B*T total
    int b = idx >> 12;                          // T_ = 4096
    float m = mden[b * 2 + 0];
    float inv = 1.0f / mden[b * 2 + 1];
    out_align[idx] = __expf(scores[idx] - m) * inv;
}

extern "C" void kernel_launch(void* const* d_in, const int* in_sizes, int n_in,
                              void* d_out, int out_size, void* d_ws, size_t ws_size,
                              hipStream_t stream) {
    const float* dec    = (const float*)d_in[0];
    const float* enc    = (const float*)d_in[1];
    const float* align  = (const float*)d_in[2];
    const float* conv_w = (const float*)d_in[3];
    const float* conv_b = (const float*)d_in[4];
    const float* W      = (const float*)d_in[5];
    const float* V      = (const float*)d_in[6];
    const float* U      = (const float*)d_in[7];
    const float* bvec   = (const float*)d_in[8];
    const float* wvec   = (const float*)d_in[9];
    float* out       = (float*)d_out;           // output[B,H] fp32
    float* out_align = out + B_ * H_;           // alignment[B,T] fp32

    char* ws = (char*)d_ws;
    float*  dpb    = (float*)(ws);                   // 64 KB
    float*  scores = (float*)(ws + (64 << 10));      // 512 KB
    float*  ml_buf = (float*)(ws + (576 << 10));     // 16 KB
    float*  u_buf  = (float*)(ws + (592 << 10));     // 4 MB
    __bf16* Vsall  = (__bf16*)(ws + (592 << 10) + (4 << 20));   // 544 KB
    float*  mden   = (float*)(ws + (592 << 10) + (4 << 20) + (544 << 10));  // 256 B

    prep_kernel<<<(B_ * A_ + A_ * H_ + A_ * C_) / 256, 256, 0, stream>>>(
        dec, W, bvec, V, U, dpb, Vsall);
    scores_mfma<<<dim3(T_ / TT, B_), 512, 0, stream>>>(enc, align, conv_w, conv_b,
                                                       Vsall, dpb, wvec, scores,
                                                       ml_buf, u_buf);
    combine2_k<<<B_, 512, 0, stream>>>(ml_buf, u_buf, out, mden);
    align_k<<<(B_ * T_) / 512, 512, 0, stream>>>(scores, mden, out_align);
}

// Round 18
// 162.299 us; speedup vs baseline: 1.3002x; 1.0093x over previous
//
#include <hip/hip_runtime.h>
#include <hip/hip_bf16.h>

#define B_ 32
#define T_ 4096
#define H_ 512
#define A_ 512
#define C_ 32
#define KTOT 544            // H + C (conv folded in as K-extension)
#define NKS  (KTOT / 32)    // 17 MFMA k-steps
#define TT   64             // t-tile rows per block
#define NCH  (T_ / TT)      // 64 t-chunks per batch

typedef float f32x4 __attribute__((ext_vector_type(4)));
typedef __bf16 bf16x8 __attribute__((ext_vector_type(8)));

__device__ inline float fast_tanh(float x) {
    // tanh(x) = 1 - 2/(exp(2x)+1); exact at saturation, |err| ~1e-7
    float t = __expf(2.0f * x);
    return 1.0f - 2.0f / (t + 1.0f);
}

__device__ __forceinline__ void async16(const void* g, void* l) {
    __builtin_amdgcn_global_load_lds(
        (const __attribute__((address_space(1))) unsigned int*)g,
        (__attribute__((address_space(3))) unsigned int*)l, 16, 0, 0);
}

// ---------------- prep: dpb = dec@W^T + b ; V,U -> unified bf16 fragment buffer ----
// Vsall[(k>>3)*A + a]*8 + (k&7), k in [0,544). Per-kstep 32KB chunk contiguous.
__global__ __launch_bounds__(256) void prep_kernel(
    const float* __restrict__ dec, const float* __restrict__ W,
    const float* __restrict__ bvec, const float* __restrict__ V,
    const float* __restrict__ U,
    float* __restrict__ dpb, __bf16* __restrict__ Vsall) {
    int id = blockIdx.x * 256 + threadIdx.x;
    const int N1 = B_ * A_;          // 16384
    const int N2 = A_ * H_;          // 262144
    if (id < N1) {
        int b = id / A_, a = id % A_;
        const float* dr = dec + b * H_;
        const float* wr = W + (size_t)a * H_;
        float s = 0.f;
        #pragma unroll 8
        for (int h = 0; h < H_; ++h) s += dr[h] * wr[h];
        dpb[id] = s + bvec[a];
    } else if (id < N1 + N2) {
        int e = id - N1;
        int a = e >> 9, k = e & 511;
        Vsall[((k >> 3) * A_ + a) * 8 + (k & 7)] = (__bf16)V[(size_t)a * H_ + k];
    } else {
        int e = id - N1 - N2;        // 16384 U elements
        int a = e >> 5, c = e & 31;
        int k = H_ + c;
        Vsall[((k >> 3) * A_ + a) * 8 + (k & 7)] = (__bf16)U[a * C_ + c];
    }
}

// ---------------- fused scores + flash partials; 64x64 wave tiles; unrolled x2 ----
// 8 waves, each owns all 64 rows x an exclusive 64-col slice (4 A + 4 B reads/kstep).
// K-loop manually unrolled by 2: buffer pointers are compile-time per copy.
// setprio(1) wraps the MFMA cluster (2 desynced blocks/CU give phase diversity).
__global__ __launch_bounds__(512) void scores_mfma(
    const float* __restrict__ enc, const float* __restrict__ align,
    const float* __restrict__ conv_w, const float* __restrict__ conv_b,
    const __bf16* __restrict__ Vsall, const float* __restrict__ dpb,
    const float* __restrict__ wvec, float* __restrict__ scores,
    float* __restrict__ ml_buf, float* __restrict__ u_buf) {
    const int bx = blockIdx.x;
    const int t0 = bx * TT;
    const int b  = blockIdx.y;
    const int tid = threadIdx.x;
    const int lane = tid & 63, wid = tid >> 6;
    const int row0 = lane & 15;   // C/D a-col lane; A-frag row-within-16
    const int kg   = lane >> 4;   // k-group 0..3 within the 32-k step
    const int wcol = wid * 64;    // wave's exclusive 64-col slice

    __shared__ char smem[73728];  // A dbuf 2x4KB @0, B dbuf 2x32KB @8192
    float* spart = (float*)smem;  // [8][TT] = 2KB, aliases A after the loop
    float* eL    = (float*)(smem + 2048);   // [TT] exp values (aliases A buf 0)

    const float* encb = enc + ((size_t)b * T_ + t0) * H_;
    const int arow = tid >> 2, akgl = tid & 3;   // A staging assignment (tid<256)
    const int ag = tid ^ ((tid >> 4) & 7);       // swizzled A unit (tid<256)

    // precomputed read offsets (loop-invariant)
    int arbyte[4];
    #pragma unroll
    for (int m = 0; m < 4; ++m) {
        int row = m * 16 + row0;
        int u = row * 4 + kg;
        int g = u ^ ((u >> 4) & 7);
        arbyte[m] = g * 16;
    }
    const int brbase = (kg * (A_ * 8) + (wcol + row0) * 8) * 2;  // byte offset in B buf

    // ---- prologue: stage kstep 0 ----
    {
        __bf16* bdst = (__bf16*)(smem + 8192);
        #pragma unroll
        for (int i = 0; i < 4; ++i) {
            int u = i * 512 + tid;
            async16(Vsall + u * 8, bdst + u * 8);
        }
    }
    if (tid < 256) {
        const float* p = encb + arow * H_ + akgl * 8;
        f32x4 lo = *reinterpret_cast<const f32x4*>(p);
        f32x4 hi = *reinterpret_cast<const f32x4*>(p + 4);
        bf16x8 v;
        v[0] = (__bf16)lo.x; v[1] = (__bf16)lo.y; v[2] = (__bf16)lo.z; v[3] = (__bf16)lo.w;
        v[4] = (__bf16)hi.x; v[5] = (__bf16)hi.y; v[6] = (__bf16)hi.z; v[7] = (__bf16)hi.w;
        *reinterpret_cast<bf16x8*>((__bf16*)smem + ag * 8) = v;
    }
    __syncthreads();

    f32x4 acc[4][4];
    #pragma unroll
    for (int m = 0; m < 4; ++m)
        #pragma unroll
        for (int n = 0; n < 4; ++n) acc[m][n] = (f32x4){0.f, 0.f, 0.f, 0.f};

    // one k-step with compile-time buffer pointers
    auto kstep = [&](int ks, char* Acur, char* Anxt, char* Bcur, char* Bnxt,
                     bool stage, bool conv_step) {
        f32x4 alo, ahi;
        if (stage) {
            const __bf16* vchunk = Vsall + (size_t)(ks + 1) * (4 * A_ * 8);
            #pragma unroll
            for (int i = 0; i < 4; ++i) {
                int u = i * 512 + tid;
                async16(vchunk + u * 8, (__bf16*)Bnxt + u * 8);
            }
            if (tid < 256 && !conv_step) {
                const float* p = encb + arow * H_ + (ks + 1) * 32 + akgl * 8;
                alo = *reinterpret_cast<const f32x4*>(p);
                ahi = *reinterpret_cast<const f32x4*>(p + 4);
            }
        }
        // ---- compute: 4 A reads + 4 B reads + 16 MFMA ----
        bf16x8 afrag[4];
        #pragma unroll
        for (int m = 0; m < 4; ++m)
            afrag[m] = *reinterpret_cast<const bf16x8*>(Acur + arbyte[m]);
        __builtin_amdgcn_s_setprio(1);
        #pragma unroll
        for (int n = 0; n < 4; ++n) {
            bf16x8 bfrag = *reinterpret_cast<const bf16x8*>(Bcur + brbase + n * 256);
            #pragma unroll
            for (int m = 0; m < 4; ++m)
                acc[m][n] = __builtin_amdgcn_mfma_f32_16x16x32_bf16(afrag[m], bfrag, acc[m][n], 0, 0, 0);
        }
        __builtin_amdgcn_s_setprio(0);
        // ---- write A(ks+1) ----
        if (stage && tid < 256) {
            bf16x8 v;
            if (!conv_step) {
                v[0] = (__bf16)alo.x; v[1] = (__bf16)alo.y; v[2] = (__bf16)alo.z; v[3] = (__bf16)alo.w;
                v[4] = (__bf16)ahi.x; v[5] = (__bf16)ahi.y; v[6] = (__bf16)ahi.z; v[7] = (__bf16)ahi.w;
            } else {
                int t = t0 + arow;
                float x0 = (t > 0) ? align[b * T_ + t - 1] : 0.f;
                float x1 = align[b * T_ + t];
                float x2 = (t + 1 < T_) ? align[b * T_ + t + 1] : 0.f;
                #pragma unroll
                for (int e = 0; e < 8; ++e) {
                    int c = akgl * 8 + e;
                    v[e] = (__bf16)(conv_b[c] + conv_w[c * 3 + 0] * x0
                                  + conv_w[c * 3 + 1] * x1 + conv_w[c * 3 + 2] * x2);
                }
            }
            *reinterpret_cast<bf16x8*>(Anxt + ag * 16) = v;
        }
        __syncthreads();
    };

    char* A0 = smem;            char* A1 = smem + 4096;
    char* B0 = smem + 8192;     char* B1 = smem + 8192 + 32768;
    for (int ks2 = 0; ks2 < 8; ++ks2) {
        kstep(2 * ks2,     A0, A1, B0, B1, true, false);       // even: cur=0
        kstep(2 * ks2 + 1, A1, A0, B1, B0, true, ks2 == 7);    // odd:  cur=1
    }
    kstep(16, A0, nullptr, B0, nullptr, false, false);         // final, compute-only

    // ---- epilogue 1: tanh(acc + dpb)*w, partial-reduce over this wave's 64 cols ----
    float dval[4], wv[4];
    #pragma unroll
    for (int n = 0; n < 4; ++n) {
        int a = wcol + n * 16 + row0;
        dval[n] = dpb[b * A_ + a];
        wv[n]   = wvec[a];
    }
    #pragma unroll
    for (int m = 0; m < 4; ++m) {
        float rs[4] = {0.f, 0.f, 0.f, 0.f};
        #pragma unroll
        for (int n = 0; n < 4; ++n) {
            #pragma unroll
            for (int j = 0; j < 4; ++j) {
                float x = acc[m][n][j] + dval[n];
                rs[j] += fast_tanh(x) * wv[n];
            }
        }
        #pragma unroll
        for (int j = 0; j < 4; ++j) {
            float v = rs[j];
            v += __shfl_xor(v, 1);
            v += __shfl_xor(v, 2);
            v += __shfl_xor(v, 4);
            v += __shfl_xor(v, 8);
            if (row0 == 0) spart[wid * TT + m * 16 + kg * 4 + j] = v;
        }
    }
    __syncthreads();

    // ---- epilogue 2: chunk partials m_c, l_c ----
    if (tid < TT) {   // wave 0 exactly (TT=64)
        float s = 0.f;
        #pragma unroll
        for (int w = 0; w < 8; ++w) s += spart[w * TT + tid];
        scores[b * T_ + t0 + tid] = s;
        float mx = s;
        #pragma unroll
        for (int off = 32; off >= 1; off >>= 1) mx = fmaxf(mx, __shfl_xor(mx, off));
        float e = __expf(s - mx);
        eL[tid] = e;
        float l = e;
        #pragma unroll
        for (int off = 32; off >= 1; off >>= 1) l += __shfl_xor(l, off);
        if (tid == 0) {
            ml_buf[((size_t)b * NCH + bx) * 2 + 0] = mx;
            ml_buf[((size_t)b * NCH + bx) * 2 + 1] = l;
        }
    }
    __syncthreads();
    // ---- epilogue 3: u[h] = sum_t eL[t] * enc[t][h] ----
    {
        float u0 = 0.f, u1 = 0.f, u2 = 0.f, u3 = 0.f;
        const float* ep = encb + tid;
        #pragma unroll 4
        for (int t = 0; t < TT; t += 4) {
            u0 += eL[t]     * ep[(size_t)t * H_];
            u1 += eL[t + 1] * ep[(size_t)(t + 1) * H_];
            u2 += eL[t + 2] * ep[(size_t)(t + 2) * H_];
            u3 += eL[t + 3] * ep[(size_t)(t + 3) * H_];
        }
        u_buf[((size_t)b * NCH + bx) * H_ + tid] = (u0 + u1) + (u2 + u3);
    }
}

// ---------------- combine2: out[b][h] = sum_c w_c u_c[h] / denom; persist m_b, denom ----
__global__ __launch_bounds__(512) void combine2_k(
    const float* __restrict__ ml_buf, const float* __restrict__ u_buf,
    float* __restrict__ out, float* __restrict__ mden) {
    int b = blockIdx.x;
    int h = threadIdx.x;
    __shared__ float wsh[NCH];
    __shared__ float dsh[2];
    if (h < NCH) {
        float m = ml_buf[((size_t)b * NCH + h) * 2];
        float mb = m;
        #pragma unroll
        for (int off = 32; off >= 1; off >>= 1) mb = fmaxf(mb, __shfl_xor(mb, off));
        float w = __expf(m - mb);
        wsh[h] = w;
        float d = w * ml_buf[((size_t)b * NCH + h) * 2 + 1];
        #pragma unroll
        for (int off = 32; off >= 1; off >>= 1) d += __shfl_xor(d, off);
        if (h == 0) {
            dsh[0] = d;
            dsh[1] = mb;
            mden[b * 2 + 0] = mb;
            mden[b * 2 + 1] = d;
        }
    }
    __syncthreads();
    float acc = 0.f;
    #pragma unroll 4
    for (int c = 0; c < NCH; ++c)
        acc += wsh[c] * u_buf[((size_t)b * NCH + c) * H_ + h];
    out[b * H_ + h] = acc / dsh[0];
}

// ---------------- align_k: fully parallel elementwise alignment ----------------
__global__ __launch_bounds__(512) void align_k(
    const float* __restrict__ scores, const float* __restrict__ mden,
    float* __restrict__ out_align) {
    int idx = blockIdx.x * 512 + threadIdx.x;   // B*T total
    int b = idx >> 12;                          // T_ = 4096
    float m = mden[b * 2 + 0];
    float inv = 1.0f / mden[b * 2 + 1];
    out_align[idx] = __expf(scores[idx] - m) * inv;
}

extern "C" void kernel_launch(void* const* d_in, const int* in_sizes, int n_in,
                              void* d_out, int out_size, void* d_ws, size_t ws_size,
                              hipStream_t stream) {
    const float* dec    = (const float*)d_in[0];
    const float* enc    = (const float*)d_in[1];
    const float* align  = (const float*)d_in[2];
    const float* conv_w = (const float*)d_in[3];
    const float* conv_b = (const float*)d_in[4];
    const float* W      = (const float*)d_in[5];
    const float* V      = (const float*)d_in[6];
    const float* U      = (const float*)d_in[7];
    const float* bvec   = (const float*)d_in[8];
    const float* wvec   = (const float*)d_in[9];
    float* out       = (float*)d_out;           // output[B,H] fp32
    float* out_align = out + B_ * H_;           // alignment[B,T] fp32

    char* ws = (char*)d_ws;
    float*  dpb    = (float*)(ws);                   // 64 KB
    float*  scores = (float*)(ws + (64 << 10));      // 512 KB
    float*  ml_buf = (float*)(ws + (576 << 10));     // 16 KB
    float*  u_buf  = (float*)(ws + (592 << 10));     // 4 MB
    __bf16* Vsall  = (__bf16*)(ws + (592 << 10) + (4 << 20));   // 544 KB
    float*  mden   = (float*)(ws + (592 << 10) + (4 << 20) + (544 << 10));  // 256 B

    prep_kernel<<<(B_ * A_ + A_ * H_ + A_ * C_) / 256, 256, 0, stream>>>(
        dec, W, bvec, V, U, dpb, Vsall);
    scores_mfma<<<dim3(T_ / TT, B_), 512, 0, stream>>>(enc, align, conv_w, conv_b,
                                                       Vsall, dpb, wvec, scores,
                                                       ml_buf, u_buf);
    combine2_k<<<B_, 512, 0, stream>>>(ml_buf, u_buf, out, mden);
    align_k<<<(B_ * T_) / 512, 512, 0, stream>>>(scores, mden, out_align);
}